// Round 12
// baseline (384.302 us; speedup 1.0000x reference)
//
#include <hip/hip_runtime.h>
#include <math.h>

// Problem constants
#define BATCHc 200000

// ---- workspace layout ----
// float offsets:
#define WS_P    0        // dead after k3; overlaid by frags in kcvt
#define WS_Y    16384
#define WS_R    32768
#define WS_A    49152
#define WS_B1   65536
#define WS_D11  81920    // D11T fp32: D11T[j*128+i] = D11[i][j]
#define WS_LAM  98304    // 128 floats
#define WS_DIAGF 106752  // f32 c-major quad-padded diag: [4 tile][4 c][188]; 3008 floats
// bf16 frag arrays, ushort offsets from (ushort*)ws:
#define FB_A    0        // overlay P/Y/R region (bytes < 172032 < 196608)
#define FB_B1   16384
#define FB_C1   32768
#define FB_D12  49152
#define FB_B2   57344
#define FB_C2   65536
#define FB_D21  73728
#define FB_D22  81920    // ends 86016
#define FB_D11  197120   // float off 98560..106751 (16384 ushorts, after WS_LAM)

typedef __attribute__((ext_vector_type(8))) short s16x8;
typedef __attribute__((ext_vector_type(8))) unsigned short u16x8;
typedef __attribute__((ext_vector_type(4))) float f32x4;
#define MFMA __builtin_amdgcn_mfma_f32_16x16x32_bf16

__device__ __forceinline__ float fast_tanh(float x) {
  float e = __expf(2.0f * x);
  return 1.0f - 2.0f * __builtin_amdgcn_rcpf(e + 1.0f);  // e+1>=1 -> rcp in (0,1], no NaN
}
__device__ __forceinline__ ushort f2bf(float f) {
  unsigned int u = __builtin_bit_cast(unsigned int, f);
  u = (u + 0x7FFFu + ((u >> 16) & 1u)) >> 16;
  return (ushort)u;
}
__device__ __forceinline__ float bf2f(ushort h) {
  return __builtin_bit_cast(float, (unsigned int)h << 16);
}
// 4-lane (quad) butterfly reduce via DPP quad_perm — VALU-latency, no LDS
__device__ __forceinline__ float qreduce(float x) {
  int a = __builtin_amdgcn_mov_dpp(__builtin_bit_cast(int, x), 0xB1, 0xF, 0xF, true);
  x += __builtin_bit_cast(float, a);
  int b = __builtin_amdgcn_mov_dpp(__builtin_bit_cast(int, x), 0x4E, 0xF, 0xF, true);
  x += __builtin_bit_cast(float, b);
  return x;
}

// frag index for matrix (N x K) row-major, element (n,k):
__device__ __forceinline__ int frag_idx(int n, int k, int KS) {
  int lane = (n & 15) + (((k >> 3) & 3) << 4);
  return ((((n >> 4) * KS + (k >> 5)) << 6) + lane) * 8 + (k & 7);
}

// K1: P, Y, R, lam, D11T into ws.
__global__ __launch_bounds__(256) void k1_params(
    const float* __restrict__ Pstar, const float* __restrict__ Chi,
    const float* __restrict__ Y1, const float* __restrict__ X,
    float* __restrict__ ws)
{
  int gid = blockIdx.x * 256 + threadIdx.x;
  int mat = gid >> 14;
  int idx = gid & 16383;
  int i = idx >> 7, j = idx & 127;
  if (mat == 0) {
    float s = 0.f;
    for (int k = 0; k < 128; ++k) s = fmaf(Pstar[i*128+k], Pstar[j*128+k], s);
    ws[WS_P + idx] = 0.5f*s + (i==j ? 0.01f : 0.f);
  } else if (mat == 1) {
    float s = 0.f;
    for (int k = 0; k < 256; ++k) s = fmaf(X[i*256+k], X[j*256+k], s);
    float h1 = s + (i==j ? 0.01f : 0.f);
    ws[WS_Y + idx] = -0.5f*(h1 + Y1[i*128+j] - Y1[j*128+i]);
  } else if (mat == 2) {
    float s = 0.f;
    for (int k = 0; k < 256; ++k) s = fmaf(X[i*256+k], X[(128+j)*256+k], s);
    ws[WS_R + idx] = -s - Chi[i*128+j];
  } else if (mat == 3) {
    if (j == 0) {
      float lam = 0.f;
      for (int k = 0; k < 256; ++k) { float v = X[(128+i)*256+k]; lam = fmaf(v, v, lam); }
      ws[WS_LAM + i] = 0.5f*(lam + 0.01f);
    }
  } else {
    float lam = 0.f, s = 0.f;
    for (int k = 0; k < 256; ++k) {
      float vi = X[(128+i)*256+k];
      lam = fmaf(vi, vi, lam);
      s = fmaf(vi, X[(128+j)*256+k], s);
    }
    lam = 0.5f*(lam + 0.01f);
    ws[WS_D11 + j*128 + i] = (j < i) ? (-s / lam) : 0.f;
  }
}

// K2: Gauss-Jordan inversion of P (SPD, no pivoting), 1 block x 512 threads.
// Matrix held in REGISTERS: thread (i = t>>2, jb = (t&3)*32) owns row i,
// cols jb..jb+31. 2 barriers/iter, no LDS matrix traffic.
__global__ __launch_bounds__(512) void k2_invert(float* __restrict__ ws)
{
  __shared__ __align__(16) float fcol[128];
  __shared__ __align__(16) float frow[128];
  const int t  = threadIdx.x;
  const int i  = t >> 2;
  const int jb = (t & 3) * 32;

  float areg[32];
  #pragma unroll
  for (int c4 = 0; c4 < 8; ++c4) {
    float4 v = *(const float4*)&ws[WS_P + i*128 + jb + c4*4];
    areg[c4*4+0]=v.x; areg[c4*4+1]=v.y; areg[c4*4+2]=v.z; areg[c4*4+3]=v.w;
  }

  for (int k = 0; k < 128; ++k) {
    if (i == k) {
      #pragma unroll
      for (int c4 = 0; c4 < 8; ++c4) {
        float4 v = {areg[c4*4+0], areg[c4*4+1], areg[c4*4+2], areg[c4*4+3]};
        *(float4*)&frow[jb + c4*4] = v;
      }
    }
    {
      float av = 0.f;
      #pragma unroll
      for (int c = 0; c < 32; ++c) av = (jb + c == k) ? areg[c] : av;
      if ((unsigned)(k - jb) < 32u) fcol[i] = av;
    }
    __syncthreads();

    const float pinv = 1.0f / fcol[k];
    const bool prow = (i == k);
    const float fp = fcol[i] * pinv;
    float fr[32];
    #pragma unroll
    for (int c4 = 0; c4 < 8; ++c4) {
      float4 v = *(const float4*)&frow[jb + c4*4];
      fr[c4*4+0]=v.x; fr[c4*4+1]=v.y; fr[c4*4+2]=v.z; fr[c4*4+3]=v.w;
    }
    #pragma unroll
    for (int c = 0; c < 32; ++c) {
      float nv = prow ? (fr[c] * pinv) : fmaf(-fp, fr[c], areg[c]);
      areg[c] = (jb + c == k) ? (prow ? pinv : -fp) : nv;
    }
    __syncthreads();
  }

  #pragma unroll
  for (int c4 = 0; c4 < 8; ++c4) {
    float4 v = {areg[c4*4+0], areg[c4*4+1], areg[c4*4+2], areg[c4*4+3]};
    *(float4*)&ws[WS_P + i*128 + jb + c4*4] = v;
  }
}

// K3: A = Pinv@Y, B1 = Pinv@R.
__global__ __launch_bounds__(256) void k3_solve(float* __restrict__ ws)
{
  const int i = blockIdx.x;
  const int t = threadIdx.x;
  const int j = t & 127;
  const int which = t >> 7;
  const float* Pinv = ws + WS_P;
  const float* Src  = ws + (which ? WS_R : WS_Y);
  float* Dst        = ws + (which ? WS_B1 : WS_A);
  float s = 0.f;
  for (int k = 0; k < 128; ++k) s = fmaf(Pinv[i*128+k], Src[k*128+j], s);
  Dst[i*128+j] = s;
}

// KCVT: pack all GEMM B-operand matrices into bf16 frag arrays + f32 c-major diag.
__global__ __launch_bounds__(256) void kcvt(
    const float* __restrict__ Chi, const float* __restrict__ D12,
    const float* __restrict__ B2, const float* __restrict__ C2,
    const float* __restrict__ D21, const float* __restrict__ D22,
    float* __restrict__ ws)
{
  int gid = blockIdx.x * 256 + threadIdx.x;
  ushort* dstb = (ushort*)ws;
  if (gid >= 102400) {
    // f32 c-major quad-padded diag: [tile][c][188]
    // slots(il) = 4 for il<=16, 8 for il>=17; soff(il) = il<=17 ? 4il : 68+8(il-17)
    int l = gid - 102400;
    if (l >= 3008) return;
    int t4  = l / 752;
    int rem = l % 752;
    int c   = rem / 188;
    int s   = rem % 188;
    int il  = (s < 68) ? (s >> 2) : (17 + ((s - 68) >> 3));
    int k   = (s < 68) ? (s & 3)  : ((s - 68) & 7);
    int jj  = 4*k + c;                       // column within tile
    float v = (jj < il) ? ws[WS_D11 + (t4*32 + jj)*128 + (t4*32 + il)] : 0.f;
    ws[WS_DIAGF + l] = v;
    return;
  }
  float val; int n, k, KS, dst;
  if (gid < 16384)      { int l = gid;        n=l>>7; k=l&127; KS=4; val = ws[WS_A + l];  dst = FB_A; }
  else if (gid < 32768) { int l = gid-16384;  n=l>>7; k=l&127; KS=4; val = ws[WS_B1 + l]; dst = FB_B1; }
  else if (gid < 49152) { int l = gid-32768;  n=l>>7; k=l&127; KS=4;
                          val = Chi[k*128+n] / ws[WS_LAM + n];        dst = FB_C1; }
  else if (gid < 57344) { int l = gid-49152;  n=l>>6; k=l&63;  KS=2; val = D12[l]; dst = FB_D12; }
  else if (gid < 65536) { int l = gid-57344;  n=l>>6; k=l&63;  KS=2; val = B2[l];  dst = FB_B2; }
  else if (gid < 73728) { int l = gid-65536;  n=l>>7; k=l&127; KS=4; val = C2[l];  dst = FB_C2; }
  else if (gid < 81920) { int l = gid-73728;  n=l>>7; k=l&127; KS=4; val = D21[l]; dst = FB_D21; }
  else if (gid < 86016) { int l = gid-81920;  n=l>>6; k=l&63;  KS=2; val = D22[l]; dst = FB_D22; }
  else                  { int l = gid-86016;  n=l>>7; k=l&127; KS=4;
                          val = ws[WS_D11 + k*128 + n];               dst = FB_D11; }  // D11[n][k]
  dstb[dst + frag_idx(n, k, KS)] = f2bf(val);
}

// ---- K4 LDS layout (bytes) ----
#define LDS_W    0       // w bf16 A-frags [4 m][4 ks][64 lane][8] = 16384
#define LDS_BW   16384   // base bf16 [64][132] ushort = 16896
#define LDS_DIAG 33280   // f32 diag [4][4][188] = 12032
#define LDS_TOT  45312   // 3 blocks/CU

// K4: fused forward, 64 batch rows/block, 4 waves, wave g owns rows 16g..16g+15.
// Barrier-free after diag staging: all LDS traffic is wave-local.
__global__ __launch_bounds__(256, 3) void k4_forward(
    const float* __restrict__ xi, const float* __restrict__ u,
    const float* __restrict__ ws,
    float* __restrict__ out)
{
  __shared__ __align__(16) char smem[LDS_TOT];
  ushort* sbw   = (ushort*)(smem + LDS_BW);
  ushort* wfr   = (ushort*)(smem + LDS_W);
  const float* sdiagf = (const float*)(smem + LDS_DIAG);
  const ushort* wsb = (const ushort*)ws;

  const int tid  = threadIdx.x;
  const int lane = tid & 63;
  const int g    = __builtin_amdgcn_readfirstlane(tid >> 6);
  const int row0 = blockIdx.x * 64;

  // stage f32 diag (752 float4s, coalesced)
  #pragma unroll
  for (int it = 0; it < 3; ++it) {
    int idx = it*256 + tid;
    if (idx < 752)
      *(float4*)(smem + LDS_DIAG + idx*16) = *(const float4*)(ws + WS_DIAGF + idx*4);
  }

  // ---- load xi/u A-frags directly global -> registers (bf16) ----
  s16x8 xif[4], uf[2];
  {
    const int r  = row0 + g*16 + (lane & 15);
    const int c0 = (lane >> 4) << 3;
    #pragma unroll
    for (int ks = 0; ks < 4; ++ks) {
      float4 a = *(const float4*)(xi + (size_t)r*128 + ks*32 + c0);
      float4 b = *(const float4*)(xi + (size_t)r*128 + ks*32 + c0 + 4);
      s16x8 f;
      f[0]=(short)f2bf(a.x); f[1]=(short)f2bf(a.y); f[2]=(short)f2bf(a.z); f[3]=(short)f2bf(a.w);
      f[4]=(short)f2bf(b.x); f[5]=(short)f2bf(b.y); f[6]=(short)f2bf(b.z); f[7]=(short)f2bf(b.w);
      xif[ks] = f;
    }
    #pragma unroll
    for (int ks = 0; ks < 2; ++ks) {
      float4 a = *(const float4*)(u + (size_t)r*64 + ks*32 + c0);
      float4 b = *(const float4*)(u + (size_t)r*64 + ks*32 + c0 + 4);
      s16x8 f;
      f[0]=(short)f2bf(a.x); f[1]=(short)f2bf(a.y); f[2]=(short)f2bf(a.z); f[3]=(short)f2bf(a.w);
      f[4]=(short)f2bf(b.x); f[5]=(short)f2bf(b.y); f[6]=(short)f2bf(b.z); f[7]=(short)f2bf(b.w);
      uf[ks] = f;
    }
  }
  __syncthreads();   // diag visible; last barrier in the kernel

  const int rl = (lane >> 4) * 4;   // C/D row base
  const int cl = lane & 15;         // C/D col

  // ---- base = xi@C1^T + u@D12^T (MFMA) -> s_bw bf16 ----
  {
    f32x4 acc[8];
    #pragma unroll
    for (int nt = 0; nt < 8; ++nt) acc[nt] = (f32x4){0.f,0.f,0.f,0.f};
    #pragma unroll
    for (int ks = 0; ks < 4; ++ks)
      #pragma unroll
      for (int nt = 0; nt < 8; ++nt) {
        s16x8 bf = *(const s16x8*)(wsb + FB_C1 + ((((nt*4+ks)<<6) + lane)<<3));
        acc[nt] = MFMA(xif[ks], bf, acc[nt], 0, 0, 0);
      }
    #pragma unroll
    for (int ks = 0; ks < 2; ++ks)
      #pragma unroll
      for (int nt = 0; nt < 8; ++nt) {
        s16x8 bf = *(const s16x8*)(wsb + FB_D12 + ((((nt*2+ks)<<6) + lane)<<3));
        acc[nt] = MFMA(uf[ks], bf, acc[nt], 0, 0, 0);
      }
    #pragma unroll
    for (int nt = 0; nt < 8; ++nt)
      #pragma unroll
      for (int r = 0; r < 4; ++r)
        sbw[(g*16 + rl + r)*132 + nt*16 + cl] = f2bf(acc[nt][r]);
  }

  // ---- recurrence (wave-local): per tile t: MFMA inter-tile + 32 serial steps ----
  {
    const int c  = lane & 3;
    const int rr = g*16 + (lane >> 2);
    const int lane_lo = lane >> 2;           // rr & 15
    #pragma unroll
    for (int t = 0; t < 4; ++t) {
      const int i0 = t*32;
      if (t > 0) {
        f32x4 sig[2];
        sig[0] = (f32x4){0.f,0.f,0.f,0.f};
        sig[1] = (f32x4){0.f,0.f,0.f,0.f};
        for (int ks = 0; ks < t; ++ks) {
          s16x8 a = *(const s16x8*)(wfr + (((g*4 + ks)<<6) + lane)*8);
          #pragma unroll
          for (int q = 0; q < 2; ++q) {
            s16x8 b = *(const s16x8*)(wsb + FB_D11 + (((((2*t+q)*4 + ks)<<6) + lane)<<3));
            sig[q] = MFMA(a, b, sig[q], 0, 0, 0);
          }
        }
        #pragma unroll
        for (int q = 0; q < 2; ++q)
          #pragma unroll
          for (int r = 0; r < 4; ++r) {
            int idx = (g*16 + rl + r)*132 + i0 + q*16 + cl;
            sbw[idx] = f2bf(bf2f(sbw[idx]) + sig[q][r]);
          }
      }
      // preload base (owner-lane layout): lane c holds cols i0+4k+c
      float bse[8];
      #pragma unroll
      for (int k = 0; k < 8; ++k) bse[k] = bf2f(sbw[rr*132 + i0 + 4*k + c]);
      float wq[8];
      #pragma unroll
      for (int k = 0; k < 8; ++k) wq[k] = 0.f;
      // f32 c-major diag: lane c's quads contiguous; 1-2 ds_read_b128 per step
      const float* dt = sdiagf + (t*4 + c)*188;
      #pragma unroll
      for (int il = 0; il < 32; ++il) {
        const int soff = (il <= 17) ? 4*il : 68 + 8*(il - 17);  // static
        f32x4 d0 = *(const f32x4*)(dt + soff);
        float p0 = d0[0]*wq[0];
        p0 = fmaf(d0[1], wq[1], p0);
        p0 = fmaf(d0[2], wq[2], p0);
        p0 = fmaf(d0[3], wq[3], p0);
        if (il >= 17) {
          f32x4 d1 = *(const f32x4*)(dt + soff + 4);
          p0 = fmaf(d1[0], wq[4], p0);
          p0 = fmaf(d1[1], wq[5], p0);
          p0 = fmaf(d1[2], wq[6], p0);
          p0 = fmaf(d1[3], wq[7], p0);
        }
        p0 = qreduce(p0);                       // DPP quad reduce
        float v = fast_tanh(bse[il >> 2] + p0); // correct on owner lane
        if (c == (il & 3)) wq[il >> 2] = v;
      }
      // batch-write this tile's w as bf16 A-frags (k_abs = i0+4k+c)
      #pragma unroll
      for (int k = 0; k < 8; ++k) {
        int ka = 4*k + c;                       // within-tile k (i0 mult of 32)
        int lanep = lane_lo + (((ka >> 3) & 3) << 4);
        wfr[((((g*4 + t)<<6) + lanep)<<3) + (ka & 7)] = f2bf(wq[k]);
      }
    }
  }

  // ---- output GEMMs (MFMA): xi@A^T + w@B1^T + u@B2^T ; xi@C2^T + w@D21^T + u@D22^T ----
  f32x4 ax[8], ay[4];
  #pragma unroll
  for (int nt = 0; nt < 8; ++nt) ax[nt] = (f32x4){0.f,0.f,0.f,0.f};
  #pragma unroll
  for (int nt = 0; nt < 4; ++nt) ay[nt] = (f32x4){0.f,0.f,0.f,0.f};

  #pragma unroll
  for (int ks = 0; ks < 4; ++ks) {
    #pragma unroll
    for (int nt = 0; nt < 8; ++nt) {
      s16x8 bf = *(const s16x8*)(wsb + FB_A + ((((nt*4+ks)<<6) + lane)<<3));
      ax[nt] = MFMA(xif[ks], bf, ax[nt], 0, 0, 0);
    }
    #pragma unroll
    for (int nt = 0; nt < 4; ++nt) {
      s16x8 bf = *(const s16x8*)(wsb + FB_C2 + ((((nt*4+ks)<<6) + lane)<<3));
      ay[nt] = MFMA(xif[ks], bf, ay[nt], 0, 0, 0);
    }
  }
  #pragma unroll
  for (int ks = 0; ks < 4; ++ks) {
    s16x8 a = *(const s16x8*)(wfr + (((g*4 + ks)<<6) + lane)*8);
    #pragma unroll
    for (int nt = 0; nt < 8; ++nt) {
      s16x8 bf = *(const s16x8*)(wsb + FB_B1 + ((((nt*4+ks)<<6) + lane)<<3));
      ax[nt] = MFMA(a, bf, ax[nt], 0, 0, 0);
    }
    #pragma unroll
    for (int nt = 0; nt < 4; ++nt) {
      s16x8 bf = *(const s16x8*)(wsb + FB_D21 + ((((nt*4+ks)<<6) + lane)<<3));
      ay[nt] = MFMA(a, bf, ay[nt], 0, 0, 0);
    }
  }
  #pragma unroll
  for (int ks = 0; ks < 2; ++ks) {
    #pragma unroll
    for (int nt = 0; nt < 8; ++nt) {
      s16x8 bf = *(const s16x8*)(wsb + FB_B2 + ((((nt*2+ks)<<6) + lane)<<3));
      ax[nt] = MFMA(uf[ks], bf, ax[nt], 0, 0, 0);
    }
    #pragma unroll
    for (int nt = 0; nt < 4; ++nt) {
      s16x8 bf = *(const s16x8*)(wsb + FB_D22 + ((((nt*2+ks)<<6) + lane)<<3));
      ay[nt] = MFMA(uf[ks], bf, ay[nt], 0, 0, 0);
    }
  }

  // ---- stores (C/D layout: row = 16g + rl + r, col = nt*16 + cl) ----
  #pragma unroll
  for (int nt = 0; nt < 8; ++nt)
    #pragma unroll
    for (int r = 0; r < 4; ++r)
      out[(size_t)(row0 + g*16 + rl + r)*128 + nt*16 + cl] = ax[nt][r];
  const size_t yoff = (size_t)BATCHc * 128;
  #pragma unroll
  for (int nt = 0; nt < 4; ++nt)
    #pragma unroll
    for (int r = 0; r < 4; ++r)
      out[yoff + (size_t)(row0 + g*16 + rl + r)*64 + nt*16 + cl] = ay[nt][r];
}

extern "C" void kernel_launch(void* const* d_in, const int* in_sizes, int n_in,
                              void* d_out, int out_size, void* d_ws, size_t ws_size,
                              hipStream_t stream) {
  // inputs: 0:t 1:xi 2:u 3:Pstar 4:Chi 5:Y1 6:X 7:B2 8:D12 9:C2 10:D21 11:D22
  const float* xi    = (const float*)d_in[1];
  const float* u     = (const float*)d_in[2];
  const float* Pstar = (const float*)d_in[3];
  const float* Chi   = (const float*)d_in[4];
  const float* Y1    = (const float*)d_in[5];
  const float* X     = (const float*)d_in[6];
  const float* B2    = (const float*)d_in[7];
  const float* D12   = (const float*)d_in[8];
  const float* C2    = (const float*)d_in[9];
  const float* D21   = (const float*)d_in[10];
  const float* D22   = (const float*)d_in[11];
  float* out = (float*)d_out;
  float* ws  = (float*)d_ws;   // uses ~440 KB (<= 459 KB proven earlier)

  k1_params<<<320, 256, 0, stream>>>(Pstar, Chi, Y1, X, ws);
  k2_invert<<<1, 512, 0, stream>>>(ws);
  k3_solve<<<128, 256, 0, stream>>>(ws);
  kcvt<<<416, 256, 0, stream>>>(Chi, D12, B2, C2, D21, D22, ws);
  k4_forward<<<(BATCHc/64), 256, 0, stream>>>(xi, u, ws, out);
}

// Round 13
// 303.624 us; speedup vs baseline: 1.2657x; 1.2657x over previous
//
#include <hip/hip_runtime.h>
#include <math.h>

// Problem constants
#define BATCHc 200000

// ---- workspace layout ----
// float offsets:
#define WS_P    0        // dead after k3; overlaid by frags in kcvt
#define WS_Y    16384
#define WS_R    32768
#define WS_A    49152
#define WS_B1   65536
#define WS_D11  81920    // D11T fp32: D11T[j*128+i] = D11[i][j]
#define WS_LAM  98304    // 128 floats
#define WS_DIAGF 106752  // f32 c-major quad-padded diag: [4 tile][4 c][188]; 3008 floats
// bf16 frag arrays, ushort offsets from (ushort*)ws:
#define FB_A    0        // overlay P/Y/R region (bytes < 172032 < 196608)
#define FB_B1   16384
#define FB_C1   32768
#define FB_D12  49152
#define FB_B2   57344
#define FB_C2   65536
#define FB_D21  73728
#define FB_D22  81920    // ends 86016
#define FB_D11  197120   // float off 98560..106751 (16384 ushorts, after WS_LAM)

typedef __attribute__((ext_vector_type(8))) short s16x8;
typedef __attribute__((ext_vector_type(8))) unsigned short u16x8;
typedef __attribute__((ext_vector_type(4))) float f32x4;
#define MFMA __builtin_amdgcn_mfma_f32_16x16x32_bf16

__device__ __forceinline__ float fast_tanh(float x) {
  float e = __expf(2.0f * x);
  return 1.0f - 2.0f * __builtin_amdgcn_rcpf(e + 1.0f);  // e+1>=1 -> rcp in (0,1], no NaN
}
__device__ __forceinline__ ushort f2bf(float f) {
  unsigned int u = __builtin_bit_cast(unsigned int, f);
  u = (u + 0x7FFFu + ((u >> 16) & 1u)) >> 16;
  return (ushort)u;
}
__device__ __forceinline__ float bf2f(ushort h) {
  return __builtin_bit_cast(float, (unsigned int)h << 16);
}
// 4-lane (quad) butterfly reduce via DPP quad_perm — VALU-latency, no LDS
__device__ __forceinline__ float qreduce(float x) {
  int a = __builtin_amdgcn_mov_dpp(__builtin_bit_cast(int, x), 0xB1, 0xF, 0xF, true);
  x += __builtin_bit_cast(float, a);
  int b = __builtin_amdgcn_mov_dpp(__builtin_bit_cast(int, x), 0x4E, 0xF, 0xF, true);
  x += __builtin_bit_cast(float, b);
  return x;
}

// frag index for matrix (N x K) row-major, element (n,k):
__device__ __forceinline__ int frag_idx(int n, int k, int KS) {
  int lane = (n & 15) + (((k >> 3) & 3) << 4);
  return ((((n >> 4) * KS + (k >> 5)) << 6) + lane) * 8 + (k & 7);
}

// K1: P, Y, R, lam, D11T into ws.
__global__ __launch_bounds__(256) void k1_params(
    const float* __restrict__ Pstar, const float* __restrict__ Chi,
    const float* __restrict__ Y1, const float* __restrict__ X,
    float* __restrict__ ws)
{
  int gid = blockIdx.x * 256 + threadIdx.x;
  int mat = gid >> 14;
  int idx = gid & 16383;
  int i = idx >> 7, j = idx & 127;
  if (mat == 0) {
    float s = 0.f;
    for (int k = 0; k < 128; ++k) s = fmaf(Pstar[i*128+k], Pstar[j*128+k], s);
    ws[WS_P + idx] = 0.5f*s + (i==j ? 0.01f : 0.f);
  } else if (mat == 1) {
    float s = 0.f;
    for (int k = 0; k < 256; ++k) s = fmaf(X[i*256+k], X[j*256+k], s);
    float h1 = s + (i==j ? 0.01f : 0.f);
    ws[WS_Y + idx] = -0.5f*(h1 + Y1[i*128+j] - Y1[j*128+i]);
  } else if (mat == 2) {
    float s = 0.f;
    for (int k = 0; k < 256; ++k) s = fmaf(X[i*256+k], X[(128+j)*256+k], s);
    ws[WS_R + idx] = -s - Chi[i*128+j];
  } else if (mat == 3) {
    if (j == 0) {
      float lam = 0.f;
      for (int k = 0; k < 256; ++k) { float v = X[(128+i)*256+k]; lam = fmaf(v, v, lam); }
      ws[WS_LAM + i] = 0.5f*(lam + 0.01f);
    }
  } else {
    float lam = 0.f, s = 0.f;
    for (int k = 0; k < 256; ++k) {
      float vi = X[(128+i)*256+k];
      lam = fmaf(vi, vi, lam);
      s = fmaf(vi, X[(128+j)*256+k], s);
    }
    lam = 0.5f*(lam + 0.01f);
    ws[WS_D11 + j*128 + i] = (j < i) ? (-s / lam) : 0.f;
  }
}

// K2: Gauss-Jordan inversion of P (SPD, no pivoting), 1 block x 512 threads.
__global__ __launch_bounds__(512) void k2_invert(float* __restrict__ ws)
{
  __shared__ __align__(16) float fcol[128];
  __shared__ __align__(16) float frow[128];
  const int t  = threadIdx.x;
  const int i  = t >> 2;
  const int jb = (t & 3) * 32;

  float areg[32];
  #pragma unroll
  for (int c4 = 0; c4 < 8; ++c4) {
    float4 v = *(const float4*)&ws[WS_P + i*128 + jb + c4*4];
    areg[c4*4+0]=v.x; areg[c4*4+1]=v.y; areg[c4*4+2]=v.z; areg[c4*4+3]=v.w;
  }

  for (int k = 0; k < 128; ++k) {
    if (i == k) {
      #pragma unroll
      for (int c4 = 0; c4 < 8; ++c4) {
        float4 v = {areg[c4*4+0], areg[c4*4+1], areg[c4*4+2], areg[c4*4+3]};
        *(float4*)&frow[jb + c4*4] = v;
      }
    }
    {
      float av = 0.f;
      #pragma unroll
      for (int c = 0; c < 32; ++c) av = (jb + c == k) ? areg[c] : av;
      if ((unsigned)(k - jb) < 32u) fcol[i] = av;
    }
    __syncthreads();

    const float pinv = 1.0f / fcol[k];
    const bool prow = (i == k);
    const float fp = fcol[i] * pinv;
    float fr[32];
    #pragma unroll
    for (int c4 = 0; c4 < 8; ++c4) {
      float4 v = *(const float4*)&frow[jb + c4*4];
      fr[c4*4+0]=v.x; fr[c4*4+1]=v.y; fr[c4*4+2]=v.z; fr[c4*4+3]=v.w;
    }
    #pragma unroll
    for (int c = 0; c < 32; ++c) {
      float nv = prow ? (fr[c] * pinv) : fmaf(-fp, fr[c], areg[c]);
      areg[c] = (jb + c == k) ? (prow ? pinv : -fp) : nv;
    }
    __syncthreads();
  }

  #pragma unroll
  for (int c4 = 0; c4 < 8; ++c4) {
    float4 v = {areg[c4*4+0], areg[c4*4+1], areg[c4*4+2], areg[c4*4+3]};
    *(float4*)&ws[WS_P + i*128 + jb + c4*4] = v;
  }
}

// K3: A = Pinv@Y, B1 = Pinv@R.
__global__ __launch_bounds__(256) void k3_solve(float* __restrict__ ws)
{
  const int i = blockIdx.x;
  const int t = threadIdx.x;
  const int j = t & 127;
  const int which = t >> 7;
  const float* Pinv = ws + WS_P;
  const float* Src  = ws + (which ? WS_R : WS_Y);
  float* Dst        = ws + (which ? WS_B1 : WS_A);
  float s = 0.f;
  for (int k = 0; k < 128; ++k) s = fmaf(Pinv[i*128+k], Src[k*128+j], s);
  Dst[i*128+j] = s;
}

// KCVT: pack all GEMM B-operand matrices into bf16 frag arrays + f32 c-major diag.
__global__ __launch_bounds__(256) void kcvt(
    const float* __restrict__ Chi, const float* __restrict__ D12,
    const float* __restrict__ B2, const float* __restrict__ C2,
    const float* __restrict__ D21, const float* __restrict__ D22,
    float* __restrict__ ws)
{
  int gid = blockIdx.x * 256 + threadIdx.x;
  ushort* dstb = (ushort*)ws;
  if (gid >= 102400) {
    // f32 c-major quad-padded diag: [tile][c][188]
    // slots(il) = 4 for il<=16, 8 for il>=17; soff(il) = il<=17 ? 4il : 68+8(il-17)
    int l = gid - 102400;
    if (l >= 3008) return;
    int t4  = l / 752;
    int rem = l % 752;
    int c   = rem / 188;
    int s   = rem % 188;
    int il  = (s < 68) ? (s >> 2) : (17 + ((s - 68) >> 3));
    int k   = (s < 68) ? (s & 3)  : ((s - 68) & 7);
    int jj  = 4*k + c;                       // column within tile
    float v = (jj < il) ? ws[WS_D11 + (t4*32 + jj)*128 + (t4*32 + il)] : 0.f;
    ws[WS_DIAGF + l] = v;
    return;
  }
  float val; int n, k, KS, dst;
  if (gid < 16384)      { int l = gid;        n=l>>7; k=l&127; KS=4; val = ws[WS_A + l];  dst = FB_A; }
  else if (gid < 32768) { int l = gid-16384;  n=l>>7; k=l&127; KS=4; val = ws[WS_B1 + l]; dst = FB_B1; }
  else if (gid < 49152) { int l = gid-32768;  n=l>>7; k=l&127; KS=4;
                          val = Chi[k*128+n] / ws[WS_LAM + n];        dst = FB_C1; }
  else if (gid < 57344) { int l = gid-49152;  n=l>>6; k=l&63;  KS=2; val = D12[l]; dst = FB_D12; }
  else if (gid < 65536) { int l = gid-57344;  n=l>>6; k=l&63;  KS=2; val = B2[l];  dst = FB_B2; }
  else if (gid < 73728) { int l = gid-65536;  n=l>>7; k=l&127; KS=4; val = C2[l];  dst = FB_C2; }
  else if (gid < 81920) { int l = gid-73728;  n=l>>7; k=l&127; KS=4; val = D21[l]; dst = FB_D21; }
  else if (gid < 86016) { int l = gid-81920;  n=l>>6; k=l&63;  KS=2; val = D22[l]; dst = FB_D22; }
  else                  { int l = gid-86016;  n=l>>7; k=l&127; KS=4;
                          val = ws[WS_D11 + k*128 + n];               dst = FB_D11; }  // D11[n][k]
  dstb[dst + frag_idx(n, k, KS)] = f2bf(val);
}

// ---- K4 LDS layout (bytes) ----
#define LDS_W    0       // w bf16 A-frags [4 m][4 ks][64 lane][8] = 16384
#define LDS_BW   16384   // base bf16 [64][132] ushort = 16896
#define LDS_DIAG 33280   // f32 diag [4][4][188] = 12032
#define LDS_TOT  45312   // 3 blocks/CU

// K4: fused forward, 64 batch rows/block, 4 waves, wave g owns rows 16g..16g+15.
// Barrier-free after diag staging: all LDS traffic is wave-local.
// R13: recurrence tile loop ROLLED (#pragma unroll 1) — 1 copy of the 32-step
// body instead of 4, shrinking hot code ~4x (icache-thrash theory).
__global__ __launch_bounds__(256, 3) void k4_forward(
    const float* __restrict__ xi, const float* __restrict__ u,
    const float* __restrict__ ws,
    float* __restrict__ out)
{
  __shared__ __align__(16) char smem[LDS_TOT];
  ushort* sbw   = (ushort*)(smem + LDS_BW);
  ushort* wfr   = (ushort*)(smem + LDS_W);
  const float* sdiagf = (const float*)(smem + LDS_DIAG);
  const ushort* wsb = (const ushort*)ws;

  const int tid  = threadIdx.x;
  const int lane = tid & 63;
  const int g    = __builtin_amdgcn_readfirstlane(tid >> 6);
  const int row0 = blockIdx.x * 64;

  // stage f32 diag (752 float4s, coalesced)
  #pragma unroll
  for (int it = 0; it < 3; ++it) {
    int idx = it*256 + tid;
    if (idx < 752)
      *(float4*)(smem + LDS_DIAG + idx*16) = *(const float4*)(ws + WS_DIAGF + idx*4);
  }

  // ---- load xi/u A-frags directly global -> registers (bf16) ----
  s16x8 xif[4], uf[2];
  {
    const int r  = row0 + g*16 + (lane & 15);
    const int c0 = (lane >> 4) << 3;
    #pragma unroll
    for (int ks = 0; ks < 4; ++ks) {
      float4 a = *(const float4*)(xi + (size_t)r*128 + ks*32 + c0);
      float4 b = *(const float4*)(xi + (size_t)r*128 + ks*32 + c0 + 4);
      s16x8 f;
      f[0]=(short)f2bf(a.x); f[1]=(short)f2bf(a.y); f[2]=(short)f2bf(a.z); f[3]=(short)f2bf(a.w);
      f[4]=(short)f2bf(b.x); f[5]=(short)f2bf(b.y); f[6]=(short)f2bf(b.z); f[7]=(short)f2bf(b.w);
      xif[ks] = f;
    }
    #pragma unroll
    for (int ks = 0; ks < 2; ++ks) {
      float4 a = *(const float4*)(u + (size_t)r*64 + ks*32 + c0);
      float4 b = *(const float4*)(u + (size_t)r*64 + ks*32 + c0 + 4);
      s16x8 f;
      f[0]=(short)f2bf(a.x); f[1]=(short)f2bf(a.y); f[2]=(short)f2bf(a.z); f[3]=(short)f2bf(a.w);
      f[4]=(short)f2bf(b.x); f[5]=(short)f2bf(b.y); f[6]=(short)f2bf(b.z); f[7]=(short)f2bf(b.w);
      uf[ks] = f;
    }
  }
  __syncthreads();   // diag visible; last barrier in the kernel

  const int rl = (lane >> 4) * 4;   // C/D row base
  const int cl = lane & 15;         // C/D col

  // ---- base = xi@C1^T + u@D12^T (MFMA) -> s_bw bf16 ----
  {
    f32x4 acc[8];
    #pragma unroll
    for (int nt = 0; nt < 8; ++nt) acc[nt] = (f32x4){0.f,0.f,0.f,0.f};
    #pragma unroll
    for (int ks = 0; ks < 4; ++ks)
      #pragma unroll
      for (int nt = 0; nt < 8; ++nt) {
        s16x8 bf = *(const s16x8*)(wsb + FB_C1 + ((((nt*4+ks)<<6) + lane)<<3));
        acc[nt] = MFMA(xif[ks], bf, acc[nt], 0, 0, 0);
      }
    #pragma unroll
    for (int ks = 0; ks < 2; ++ks)
      #pragma unroll
      for (int nt = 0; nt < 8; ++nt) {
        s16x8 bf = *(const s16x8*)(wsb + FB_D12 + ((((nt*2+ks)<<6) + lane)<<3));
        acc[nt] = MFMA(uf[ks], bf, acc[nt], 0, 0, 0);
      }
    #pragma unroll
    for (int nt = 0; nt < 8; ++nt)
      #pragma unroll
      for (int r = 0; r < 4; ++r)
        sbw[(g*16 + rl + r)*132 + nt*16 + cl] = f2bf(acc[nt][r]);
  }

  // ---- recurrence (wave-local): per tile t: MFMA inter-tile + 32 serial steps ----
  {
    const int c  = lane & 3;
    const int rr = g*16 + (lane >> 2);
    const int lane_lo = lane >> 2;           // rr & 15
    #pragma unroll 1                         // ROLLED: one copy of the body
    for (int t = 0; t < 4; ++t) {
      const int i0 = t*32;
      if (t > 0) {
        f32x4 sig[2];
        sig[0] = (f32x4){0.f,0.f,0.f,0.f};
        sig[1] = (f32x4){0.f,0.f,0.f,0.f};
        #pragma unroll 1
        for (int ks = 0; ks < t; ++ks) {
          s16x8 a = *(const s16x8*)(wfr + (((g*4 + ks)<<6) + lane)*8);
          #pragma unroll
          for (int q = 0; q < 2; ++q) {
            s16x8 b = *(const s16x8*)(wsb + FB_D11 + (((((2*t+q)*4 + ks)<<6) + lane)<<3));
            sig[q] = MFMA(a, b, sig[q], 0, 0, 0);
          }
        }
        #pragma unroll
        for (int q = 0; q < 2; ++q)
          #pragma unroll
          for (int r = 0; r < 4; ++r) {
            int idx = (g*16 + rl + r)*132 + i0 + q*16 + cl;
            sbw[idx] = f2bf(bf2f(sbw[idx]) + sig[q][r]);
          }
      }
      // preload base (owner-lane layout): lane c holds cols i0+4k+c
      float bse[8];
      #pragma unroll
      for (int k = 0; k < 8; ++k) bse[k] = bf2f(sbw[rr*132 + i0 + 4*k + c]);
      float wq[8];
      #pragma unroll
      for (int k = 0; k < 8; ++k) wq[k] = 0.f;
      // f32 c-major diag: lane c's quads contiguous; 1-2 ds_read_b128 per step
      const float* dt = sdiagf + (t*4 + c)*188;
      #pragma unroll
      for (int il = 0; il < 32; ++il) {
        const int soff = (il <= 17) ? 4*il : 68 + 8*(il - 17);  // static
        f32x4 d0 = *(const f32x4*)(dt + soff);
        float p0 = d0[0]*wq[0];
        p0 = fmaf(d0[1], wq[1], p0);
        p0 = fmaf(d0[2], wq[2], p0);
        p0 = fmaf(d0[3], wq[3], p0);
        if (il >= 17) {
          f32x4 d1 = *(const f32x4*)(dt + soff + 4);
          p0 = fmaf(d1[0], wq[4], p0);
          p0 = fmaf(d1[1], wq[5], p0);
          p0 = fmaf(d1[2], wq[6], p0);
          p0 = fmaf(d1[3], wq[7], p0);
        }
        p0 = qreduce(p0);                       // DPP quad reduce
        float v = fast_tanh(bse[il >> 2] + p0); // correct on owner lane
        if (c == (il & 3)) wq[il >> 2] = v;
      }
      // batch-write this tile's w as bf16 A-frags (k_abs = i0+4k+c)
      #pragma unroll
      for (int k = 0; k < 8; ++k) {
        int ka = 4*k + c;                       // within-tile k (i0 mult of 32)
        int lanep = lane_lo + (((ka >> 3) & 3) << 4);
        wfr[((((g*4 + t)<<6) + lanep)<<3) + (ka & 7)] = f2bf(wq[k]);
      }
    }
  }

  // ---- output GEMMs (MFMA): xi@A^T + w@B1^T + u@B2^T ; xi@C2^T + w@D21^T + u@D22^T ----
  f32x4 ax[8], ay[4];
  #pragma unroll
  for (int nt = 0; nt < 8; ++nt) ax[nt] = (f32x4){0.f,0.f,0.f,0.f};
  #pragma unroll
  for (int nt = 0; nt < 4; ++nt) ay[nt] = (f32x4){0.f,0.f,0.f,0.f};

  #pragma unroll
  for (int ks = 0; ks < 4; ++ks) {
    #pragma unroll
    for (int nt = 0; nt < 8; ++nt) {
      s16x8 bf = *(const s16x8*)(wsb + FB_A + ((((nt*4+ks)<<6) + lane)<<3));
      ax[nt] = MFMA(xif[ks], bf, ax[nt], 0, 0, 0);
    }
    #pragma unroll
    for (int nt = 0; nt < 4; ++nt) {
      s16x8 bf = *(const s16x8*)(wsb + FB_C2 + ((((nt*4+ks)<<6) + lane)<<3));
      ay[nt] = MFMA(xif[ks], bf, ay[nt], 0, 0, 0);
    }
  }
  #pragma unroll
  for (int ks = 0; ks < 4; ++ks) {
    s16x8 a = *(const s16x8*)(wfr + (((g*4 + ks)<<6) + lane)*8);
    #pragma unroll
    for (int nt = 0; nt < 8; ++nt) {
      s16x8 bf = *(const s16x8*)(wsb + FB_B1 + ((((nt*4+ks)<<6) + lane)<<3));
      ax[nt] = MFMA(a, bf, ax[nt], 0, 0, 0);
    }
    #pragma unroll
    for (int nt = 0; nt < 4; ++nt) {
      s16x8 bf = *(const s16x8*)(wsb + FB_D21 + ((((nt*4+ks)<<6) + lane)<<3));
      ay[nt] = MFMA(a, bf, ay[nt], 0, 0, 0);
    }
  }
  #pragma unroll
  for (int ks = 0; ks < 2; ++ks) {
    #pragma unroll
    for (int nt = 0; nt < 8; ++nt) {
      s16x8 bf = *(const s16x8*)(wsb + FB_B2 + ((((nt*2+ks)<<6) + lane)<<3));
      ax[nt] = MFMA(uf[ks], bf, ax[nt], 0, 0, 0);
    }
    #pragma unroll
    for (int nt = 0; nt < 4; ++nt) {
      s16x8 bf = *(const s16x8*)(wsb + FB_D22 + ((((nt*2+ks)<<6) + lane)<<3));
      ay[nt] = MFMA(uf[ks], bf, ay[nt], 0, 0, 0);
    }
  }

  // ---- stores (C/D layout: row = 16g + rl + r, col = nt*16 + cl) ----
  #pragma unroll
  for (int nt = 0; nt < 8; ++nt)
    #pragma unroll
    for (int r = 0; r < 4; ++r)
      out[(size_t)(row0 + g*16 + rl + r)*128 + nt*16 + cl] = ax[nt][r];
  const size_t yoff = (size_t)BATCHc * 128;
  #pragma unroll
  for (int nt = 0; nt < 4; ++nt)
    #pragma unroll
    for (int r = 0; r < 4; ++r)
      out[yoff + (size_t)(row0 + g*16 + rl + r)*64 + nt*16 + cl] = ay[nt][r];
}

extern "C" void kernel_launch(void* const* d_in, const int* in_sizes, int n_in,
                              void* d_out, int out_size, void* d_ws, size_t ws_size,
                              hipStream_t stream) {
  // inputs: 0:t 1:xi 2:u 3:Pstar 4:Chi 5:Y1 6:X 7:B2 8:D12 9:C2 10:D21 11:D22
  const float* xi    = (const float*)d_in[1];
  const float* u     = (const float*)d_in[2];
  const float* Pstar = (const float*)d_in[3];
  const float* Chi   = (const float*)d_in[4];
  const float* Y1    = (const float*)d_in[5];
  const float* X     = (const float*)d_in[6];
  const float* B2    = (const float*)d_in[7];
  const float* D12   = (const float*)d_in[8];
  const float* C2    = (const float*)d_in[9];
  const float* D21   = (const float*)d_in[10];
  const float* D22   = (const float*)d_in[11];
  float* out = (float*)d_out;
  float* ws  = (float*)d_ws;   // uses ~440 KB (<= 459 KB proven earlier)

  k1_params<<<320, 256, 0, stream>>>(Pstar, Chi, Y1, X, ws);
  k2_invert<<<1, 512, 0, stream>>>(ws);
  k3_solve<<<128, 256, 0, stream>>>(ws);
  kcvt<<<416, 256, 0, stream>>>(Chi, D12, B2, C2, D21, D22, ws);
  k4_forward<<<(BATCHc/64), 256, 0, stream>>>(xi, u, ws, out);
}